// Round 17
// baseline (195.201 us; speedup 1.0000x reference)
//
#include <hip/hip_runtime.h>

#define PI2 6.28318530717958647692f

// D = 10000 = 100 x 100; F = 5001; signals: 128 pos + 10 atom + 1 closure = 139
#define NSIG 139
#define FS   5120      // spectrum row stride (float2)

// ---------------- fused forward (f1+f2), Hermitian-paired, LDS-resident ----------------
// Block = (sig, sixth q). Phase 1: x staged in TWO 50-row halves through one 20 KB
// buffer (recurrence carries across halves). Phase 2: B rows overlay the buffer.
// Phase 3: f2 column-DFT from LDS rows, write spec.
__global__ __launch_bounds__(256) void k_fwd(
                     const float* __restrict__ atom, const float* __restrict__ pos,
                     const float* __restrict__ clo, float2* __restrict__ spec) {
  __shared__ float xs[5000];    // phase1: 50 x-rows; phase3: B rows (stride 200 floats)
  unsigned sig = blockIdx.x, q = blockIdx.y;
  unsigned k1base = q * 10u;
  unsigned nk1 = (k1base + 10u <= 51u) ? 10u : (51u - k1base);   // q=5 -> 1 (k1=50)
  const float* xb = (sig < 128u) ? (pos + sig * 10000u)
                   : ((sig < 138u) ? (atom + (sig - 128u) * 10000u) : clo);
  int tid = threadIdx.x;
  unsigned ntile1 = nk1 * 25u;
  unsigned k1l = tid / 25u, n2 = (tid % 25u) * 4u;
  bool have = (unsigned)tid < ntile1;
  unsigned k1 = k1base + k1l;
  float cth, sth;
  __sincosf(PI2 * (float)k1 * 0.01f, &sth, &cth);
  float c = 1.0f, s = 0.0f;
  float ar[4] = {}, as[4] = {};

  for (int h = 0; h < 2; ++h) {
    for (int i = tid; i < 1250; i += 256)
      *(float4*)(xs + 4 * i) = *(const float4*)(xb + h * 5000 + 4 * i);
    __syncthreads();
    if (have) {
#pragma unroll 5
      for (int n1l = 0; n1l < 50; ++n1l) {
        const float4 xv = *(const float4*)(xs + n1l * 100 + n2);
        ar[0] += xv.x * c; as[0] += xv.x * s;
        ar[1] += xv.y * c; as[1] += xv.y * s;
        ar[2] += xv.z * c; as[2] += xv.z * s;
        ar[3] += xv.w * c; as[3] += xv.w * s;
        float cn = c * cth - s * sth;
        float sn = s * cth + c * sth;
        c = cn; s = sn;
      }
    }
    __syncthreads();
  }

  if (have) {
    unsigned rb = (100u - k1) % 100u;
    float resA[8], resB[8];
#pragma unroll
    for (int j = 0; j < 4; ++j) {
      float swA, cwA, swB, cwB;
      __sincosf(PI2 * (float)((n2 + j) * k1) * 1e-4f, &swA, &cwA);
      __sincosf(PI2 * (float)((n2 + j) * rb) * 1e-4f, &swB, &cwB);
      resA[2 * j + 0] = ar[j] * cwA - as[j] * swA;
      resA[2 * j + 1] = -(as[j] * cwA + ar[j] * swA);
      resB[2 * j + 0] = ar[j] * cwB + as[j] * swB;
      resB[2 * j + 1] = as[j] * cwB - ar[j] * swB;
    }
    float* pA = xs + k1l * 200u + n2 * 2u;
    float* pB = xs + (nk1 + k1l) * 200u + n2 * 2u;
    *(float4*)(pA + 0) = make_float4(resA[0], resA[1], resA[2], resA[3]);
    *(float4*)(pA + 4) = make_float4(resA[4], resA[5], resA[6], resA[7]);
    *(float4*)(pB + 0) = make_float4(resB[0], resB[1], resB[2], resB[3]);
    *(float4*)(pB + 4) = make_float4(resB[4], resB[5], resB[6], resB[7]);
  }
  __syncthreads();

  unsigned nrow = 2u * nk1;
  unsigned ntile3 = nrow * 26u;
  for (unsigned t = tid; t < ntile3; t += 256u) {
    unsigned lr = t / 26u, k2 = (t % 26u) * 2u;
    unsigned gk1 = (lr < nk1) ? (k1base + lr) : ((100u - (k1base + (lr - nk1))) % 100u);
    const float* brow = xs + lr * 200u;
    float cthA, sthA, cthB, sthB;
    __sincosf(PI2 * (float)k2 * 0.01f, &sthA, &cthA);
    __sincosf(PI2 * (float)(k2 + 1) * 0.01f, &sthB, &cthB);
    float cA = 1.0f, sA = 0.0f, cB = 1.0f, sB = 0.0f;
    float reA = 0.f, imA = 0.f, reB = 0.f, imB = 0.f;
#pragma unroll 4
    for (int n2i = 0; n2i < 100; n2i += 2) {
      const float4 b0 = *(const float4*)(brow + 2 * n2i);
      reA += b0.x * cA + b0.y * sA;  imA += b0.y * cA - b0.x * sA;
      reB += b0.x * cB + b0.y * sB;  imB += b0.y * cB - b0.x * sB;
      float cA1 = cA * cthA - sA * sthA, sA1 = sA * cthA + cA * sthA;
      float cB1 = cB * cthB - sB * sthB, sB1 = sB * cthB + cB * sthB;
      reA += b0.z * cA1 + b0.w * sA1;  imA += b0.w * cA1 - b0.z * sA1;
      reB += b0.z * cB1 + b0.w * sB1;  imB += b0.w * cB1 - b0.z * sB1;
      cA = cA1 * cthA - sA1 * sthA; sA = sA1 * cthA + cA1 * sthA;
      cB = cB1 * cthB - sB1 * sthB; sB = sB1 * cthB + cB1 * sthB;
    }
    unsigned kA = gk1 + 100u * k2;
    unsigned kB = gk1 + 100u * (k2 + 1);
    if (kA <= 5000u) spec[sig * FS + kA] = make_float2(reA, imA);
    if (kB <= 5000u) spec[sig * FS + kB] = make_float2(reB, imB);
  }
}

// ---------------- mix: b-tile 2, 640 blocks, serial Fp loads ----------------
__global__ void k_mix(const float2* __restrict__ spec,
                      const float* __restrict__ tmask, const float* __restrict__ rmask,
                      const int* __restrict__ aidx, const int* __restrict__ rpos,
                      float2* __restrict__ G) {
  __shared__ float2 FaS[10][256];
  __shared__ float2 FcS[256];
  __shared__ float tmS[2][128];
  __shared__ int   aiS[2][128];
  __shared__ float rmS[2][8];
  __shared__ int   rpS[2][8][2];
  int tid = threadIdx.x;
  int k = blockIdx.x * 256 + tid;
  int kc = k > 5000 ? 5000 : k;
  int b0 = blockIdx.y * 2;
#pragma unroll
  for (int a = 0; a < 10; ++a) FaS[a][tid] = spec[(128 + a) * FS + kc];
  FcS[tid] = spec[138 * FS + kc];
  for (int i = tid; i < 2 * 128; i += 256) {
    int bb = i >> 7, ss = i & 127;
    tmS[bb][ss] = tmask[(b0 + bb) * 128 + ss];
    aiS[bb][ss] = aidx[(b0 + bb) * 128 + ss];
  }
  if (tid < 16) {
    int bb = tid >> 3, rr = tid & 7;
    rmS[bb][rr] = rmask[(b0 + bb) * 8 + rr];
    rpS[bb][rr][0] = rpos[((b0 + bb) * 8 + rr) * 2 + 0];
    rpS[bb][rr][1] = rpos[((b0 + bb) * 8 + rr) * 2 + 1];
  }
  __syncthreads();
  float fr[2] = {}, fi[2] = {};
#pragma unroll 8
  for (int s = 0; s < 128; ++s) {
    float2 fp = spec[s * FS + kc];
#pragma unroll
    for (int b = 0; b < 2; ++b) {
      int a = aiS[b][s];
      float tm = tmS[b][s];
      float2 fa = FaS[a][tid];
      float tr = fa.x * fp.x - fa.y * fp.y;
      float ti = fa.x * fp.y + fa.y * fp.x;
      fr[b] += tm * tr;
      fi[b] += tm * ti;
    }
  }
  float2 fc = FcS[tid];
#pragma unroll
  for (int r = 0; r < 8; ++r) {
#pragma unroll
    for (int b = 0; b < 2; ++b) {
      int p0 = rpS[b][r][0], p1 = rpS[b][r][1];
      float rm = rmS[b][r];
      float2 f0 = spec[p0 * FS + kc];
      float2 f1 = spec[p1 * FS + kc];
      float tr = f0.x * f1.x - f0.y * f1.y;
      float ti = f0.x * f1.y + f0.y * f1.x;
      float ur = tr * fc.x - ti * fc.y;
      float ui = tr * fc.y + ti * fc.x;
      fr[b] += rm * ur;
      fi[b] += rm * ui;
    }
  }
  if (k <= 5000) {
#pragma unroll
    for (int b = 0; b < 2; ++b) {
      float fib = (k == 0 || k == 5000) ? 0.0f : fi[b];  // exact Hermitian guard
      G[(size_t)(b0 + b) * 10000 + k] = make_float2(fr[b], fib);
      if (k >= 1 && k <= 4999)
        G[(size_t)(b0 + b) * 10000 + (10000 - k)] = make_float2(fr[b], -fib);
    }
  }
}

// ---------------- fused inverse (i1+i2) per (sig, m1-decile) ----------------
// Block = (sig, md). m1 in [10*md, 10*md+10).
// Phase 1 (i1): G[sig] cols 0..51 staged in two n1-halves (20.8 KB buffer; recurrence
//   re-init at half boundary is exact: cos/sin(pi*m1) = (+-1, 0)). 260 tiles of
//   1 m1 x 2 n2, handled as UP TO 2 TILES PER THREAD (260 > 256 -- round-16 bug).
//   Epilogue-twiddle into biS[10][104] (4.2 KB).
// Phase 2 (i2): 500 tiles of 1 m1 x 2 m2 from biS; write mol. No Bi global round-trip.
__global__ __launch_bounds__(256) void k_inv(const float2* __restrict__ G,
                                             float* __restrict__ mol) {
  __shared__ float gs[5200];    // 50 G-rows x 52 complex
  __shared__ float biS[1040];   // 10 Bi-rows x 52 complex
  unsigned sig = blockIdx.x, md = blockIdx.y;
  unsigned m1base = md * 10u;
  int tid = threadIdx.x;
  const float* gp = (const float*)(G + sig * 10000u);

  float reA[2] = {}, imA[2] = {}, reB[2] = {}, imB[2] = {};

  for (int h = 0; h < 2; ++h) {
    if (h) __syncthreads();               // h=0 reads done before overwrite
    for (int i = tid; i < 1300; i += 256) {
      int row = i / 26, c4 = i % 26;
      *(float4*)(gs + row * 104 + c4 * 4) =
          *(const float4*)(gp + (h * 50 + row) * 200 + c4 * 4);
    }
    __syncthreads();
#pragma unroll
    for (int r = 0; r < 2; ++r) {
      unsigned t = (unsigned)tid + 256u * r;
      if (t >= 260u) continue;
      unsigned m1l = t / 26u, n2 = (t % 26u) * 2u;
      unsigned m1 = m1base + m1l;
      float cth, sth;
      __sincosf(PI2 * (float)m1 * 0.01f, &sth, &cth);
      float c, s;
      if (h == 0) { c = 1.0f; s = 0.0f; }
      else        { c = (m1 & 1u) ? -1.0f : 1.0f; s = 0.0f; }   // e^{i*pi*m1}, exact
      float ra = reA[r], ia = imA[r], rb = reB[r], ib = imB[r];
#pragma unroll 5
      for (int n1l = 0; n1l < 50; ++n1l) {
        const float4 gv = *(const float4*)(gs + n1l * 104 + n2 * 2);
        ra += gv.x * c - gv.y * s;  ia += gv.y * c + gv.x * s;
        rb += gv.z * c - gv.w * s;  ib += gv.w * c + gv.z * s;
        float cn = c * cth - s * sth;
        float sn = s * cth + c * sth;
        c = cn; s = sn;
      }
      reA[r] = ra; imA[r] = ia; reB[r] = rb; imB[r] = ib;
    }
  }
  // epilogue twiddle -> biS (same up-to-2-tiles mapping)
#pragma unroll
  for (int r = 0; r < 2; ++r) {
    unsigned t = (unsigned)tid + 256u * r;
    if (t >= 260u) continue;
    unsigned m1l = t / 26u, n2 = (t % 26u) * 2u;
    unsigned m1 = m1base + m1l;
    float w0 = (n2 == 0u || n2 == 50u) ? 0.5f : 1.0f;
    float w1 = (n2 == 50u) ? 0.0f : 1.0f;   // col 51 unused
    float sw0, cw0, sw1, cw1;
    __sincosf(PI2 * (float)(n2 * m1) * 1e-4f, &sw0, &cw0);
    __sincosf(PI2 * (float)((n2 + 1u) * m1) * 1e-4f, &sw1, &cw1);
    float4 outv;
    outv.x = (reA[r] * cw0 - imA[r] * sw0) * w0;
    outv.y = (imA[r] * cw0 + reA[r] * sw0) * w0;
    outv.z = (reB[r] * cw1 - imB[r] * sw1) * w1;
    outv.w = (imB[r] * cw1 + reB[r] * sw1) * w1;
    *(float4*)(biS + m1l * 104u + n2 * 2u) = outv;
  }
  __syncthreads();

  // phase 2: i2 from biS
  for (int t = tid; t < 500; t += 256) {
    unsigned l = (unsigned)t / 50u;
    unsigned m2 = ((unsigned)t % 50u) * 2u;
    const float* b0 = biS + l * 104u;
    float cthA, sthA, cthB, sthB;
    __sincosf(PI2 * (float)m2 * 0.01f, &sthA, &cthA);
    __sincosf(PI2 * (float)(m2 + 1u) * 0.01f, &sthB, &cthB);
    float cA = 1.0f, sA = 0.0f, cB = 1.0f, sB = 0.0f;
    float r0 = 0.f, r1 = 0.f;
#pragma unroll 4
    for (int jj = 0; jj < 26; ++jj) {
      int n2i = 2 * jj;
      const float4 v0 = *(const float4*)(b0 + 2 * n2i);
      r0 += v0.x * cA - v0.y * sA;
      r1 += v0.x * cB - v0.y * sB;
      float cA1 = cA * cthA - sA * sthA, sA1 = sA * cthA + cA * sthA;
      float cB1 = cB * cthB - sB * sthB, sB1 = sB * cthB + cB * sthB;
      r0 += v0.z * cA1 - v0.w * sA1;
      r1 += v0.z * cB1 - v0.w * sB1;
      cA = cA1 * cthA - sA1 * sthA; sA = sA1 * cthA + cA1 * sthA;
      cB = cB1 * cthB - sB1 * sthB; sB = sB1 * cthB + cB1 * sthB;
    }
    unsigned m1g = m1base + l;
    mol[sig * 10000u + m1g + 100u * m2] = r0 * 2e-4f;
    mol[sig * 10000u + m1g + 100u * (m2 + 1u)] = r1 * 2e-4f;
  }
}

// ---------------- projection: 250 chunks of 40 (round-13 proven) ----------------
__global__ __launch_bounds__(256) void k_proj(const float* __restrict__ mol,
                                              const float* __restrict__ W,
                                              float* __restrict__ part) {
  __shared__ float molS[40 * 64];
  int tid = threadIdx.x;
  int d0 = blockIdx.x * 40;
  for (int i = tid; i < 40 * 64; i += 256)
    molS[i] = mol[(size_t)(i & 63) * 10000 + d0 + (i >> 6)];
  __syncthreads();
  int p0 = (tid & 63) * 4;
  int bh = (tid >> 6) * 16;
  float acc[4][16] = {};
  const float* w0 = W + (size_t)(p0 + 0) * 10000 + d0;
  const float* w1 = W + (size_t)(p0 + 1) * 10000 + d0;
  const float* w2 = W + (size_t)(p0 + 2) * 10000 + d0;
  const float* w3 = W + (size_t)(p0 + 3) * 10000 + d0;
#pragma unroll 4
  for (int dl = 0; dl < 40; ++dl) {
    const float wv[4] = {w0[dl], w1[dl], w2[dl], w3[dl]};
    const float4* m4 = (const float4*)(molS + dl * 64 + bh);
#pragma unroll
    for (int q = 0; q < 4; ++q) {
      float4 mv = m4[q];
#pragma unroll
      for (int pp = 0; pp < 4; ++pp) {
        acc[pp][4 * q + 0] += wv[pp] * mv.x;
        acc[pp][4 * q + 1] += wv[pp] * mv.y;
        acc[pp][4 * q + 2] += wv[pp] * mv.z;
        acc[pp][4 * q + 3] += wv[pp] * mv.w;
      }
    }
  }
#pragma unroll
  for (int b = 0; b < 16; ++b) {
    float4 v = make_float4(acc[0][b], acc[1][b], acc[2][b], acc[3][b]);
    *(float4*)(part + (size_t)blockIdx.x * 16384 + (bh + b) * 256 + p0) = v;
  }
}

// ---------------- reduce partials + bias ----------------
__global__ void k_red(const float* __restrict__ part, const float* __restrict__ bias,
                      float* __restrict__ out) {
  int tid = threadIdx.x;
  int b = blockIdx.x;
  float acc = bias[tid];
#pragma unroll 8
  for (int ch = 0; ch < 250; ++ch)
    acc += part[(size_t)ch * 16384 + b * 256 + tid];
  out[b * 256 + tid] = acc;
}

extern "C" void kernel_launch(void* const* d_in, const int* in_sizes, int n_in,
                              void* d_out, int out_size, void* d_ws, size_t ws_size,
                              hipStream_t stream) {
  const float* atom  = (const float*)d_in[0];   // [10,10000]
  const float* pos   = (const float*)d_in[1];   // [128,10000]
  const float* clo   = (const float*)d_in[2];   // [10000]
  const float* W     = (const float*)d_in[3];   // [256,10000]
  const float* bias  = (const float*)d_in[4];   // [256]
  const float* tmask = (const float*)d_in[5];   // [64,128]
  const float* rmask = (const float*)d_in[6];   // [64,8]
  const int*   aidx  = (const int*)d_in[7];     // [64,128]
  const int*   rpos  = (const int*)d_in[8];     // [64,8,2]
  float* out = (float*)d_out;                   // [64,256]

  char* ws = (char*)d_ws;
  size_t off = 0;
  auto alloc = [&](size_t n) { off = (off + 255) & ~(size_t)255; size_t o = off; off += n; return o; };
  float*  part = (float*)(ws + alloc(16777216));            // partials (16.4MB)
  float2* spec = (float2*)(ws + alloc((size_t)NSIG * FS * 8));
  float2* G    = (float2*)(ws + alloc((size_t)64 * 10000 * 8));
  float*  mol  = (float*)(ws + alloc((size_t)64 * 10000 * 4));

  k_fwd<<<dim3(NSIG, 6), dim3(256), 0, stream>>>(atom, pos, clo, spec);
  k_mix<<<dim3(20, 32), dim3(256), 0, stream>>>(spec, tmask, rmask, aidx, rpos, G);
  k_inv<<<dim3(64, 10), dim3(256), 0, stream>>>(G, mol);
  k_proj<<<dim3(250), dim3(256), 0, stream>>>(mol, W, part);
  k_red<<<dim3(64), dim3(256), 0, stream>>>(part, bias, out);
}

// Round 18
// 190.393 us; speedup vs baseline: 1.0252x; 1.0252x over previous
//
#include <hip/hip_runtime.h>

#define PI2 6.28318530717958647692f

// D = 10000 = 100 x 100; F = 5001; signals: 128 pos + 10 atom + 1 closure = 139
#define NSIG 139
#define FS   5120      // spectrum row stride (float2)

// ---------------- fused forward (f1+f2), Hermitian-paired, LDS-resident ----------------
// Block = (sig, sixth q). Phase 1: x staged in TWO 50-row halves through one 20 KB
// buffer (recurrence carries across halves). Phase 2: B rows overlay the buffer.
// Phase 3: f2 column-DFT from LDS rows, write spec.
__global__ __launch_bounds__(256) void k_fwd(
                     const float* __restrict__ atom, const float* __restrict__ pos,
                     const float* __restrict__ clo, float2* __restrict__ spec) {
  __shared__ float xs[5000];    // phase1: 50 x-rows; phase3: B rows (stride 200 floats)
  unsigned sig = blockIdx.x, q = blockIdx.y;
  unsigned k1base = q * 10u;
  unsigned nk1 = (k1base + 10u <= 51u) ? 10u : (51u - k1base);   // q=5 -> 1 (k1=50)
  const float* xb = (sig < 128u) ? (pos + sig * 10000u)
                   : ((sig < 138u) ? (atom + (sig - 128u) * 10000u) : clo);
  int tid = threadIdx.x;
  unsigned ntile1 = nk1 * 25u;
  unsigned k1l = tid / 25u, n2 = (tid % 25u) * 4u;
  bool have = (unsigned)tid < ntile1;
  unsigned k1 = k1base + k1l;
  float cth, sth;
  __sincosf(PI2 * (float)k1 * 0.01f, &sth, &cth);
  float c = 1.0f, s = 0.0f;
  float ar[4] = {}, as[4] = {};

  for (int h = 0; h < 2; ++h) {
    for (int i = tid; i < 1250; i += 256)
      *(float4*)(xs + 4 * i) = *(const float4*)(xb + h * 5000 + 4 * i);
    __syncthreads();
    if (have) {
#pragma unroll 5
      for (int n1l = 0; n1l < 50; ++n1l) {
        const float4 xv = *(const float4*)(xs + n1l * 100 + n2);
        ar[0] += xv.x * c; as[0] += xv.x * s;
        ar[1] += xv.y * c; as[1] += xv.y * s;
        ar[2] += xv.z * c; as[2] += xv.z * s;
        ar[3] += xv.w * c; as[3] += xv.w * s;
        float cn = c * cth - s * sth;
        float sn = s * cth + c * sth;
        c = cn; s = sn;
      }
    }
    __syncthreads();
  }

  if (have) {
    unsigned rb = (100u - k1) % 100u;
    float resA[8], resB[8];
#pragma unroll
    for (int j = 0; j < 4; ++j) {
      float swA, cwA, swB, cwB;
      __sincosf(PI2 * (float)((n2 + j) * k1) * 1e-4f, &swA, &cwA);
      __sincosf(PI2 * (float)((n2 + j) * rb) * 1e-4f, &swB, &cwB);
      resA[2 * j + 0] = ar[j] * cwA - as[j] * swA;
      resA[2 * j + 1] = -(as[j] * cwA + ar[j] * swA);
      resB[2 * j + 0] = ar[j] * cwB + as[j] * swB;
      resB[2 * j + 1] = as[j] * cwB - ar[j] * swB;
    }
    float* pA = xs + k1l * 200u + n2 * 2u;
    float* pB = xs + (nk1 + k1l) * 200u + n2 * 2u;
    *(float4*)(pA + 0) = make_float4(resA[0], resA[1], resA[2], resA[3]);
    *(float4*)(pA + 4) = make_float4(resA[4], resA[5], resA[6], resA[7]);
    *(float4*)(pB + 0) = make_float4(resB[0], resB[1], resB[2], resB[3]);
    *(float4*)(pB + 4) = make_float4(resB[4], resB[5], resB[6], resB[7]);
  }
  __syncthreads();

  unsigned nrow = 2u * nk1;
  unsigned ntile3 = nrow * 26u;
  for (unsigned t = tid; t < ntile3; t += 256u) {
    unsigned lr = t / 26u, k2 = (t % 26u) * 2u;
    unsigned gk1 = (lr < nk1) ? (k1base + lr) : ((100u - (k1base + (lr - nk1))) % 100u);
    const float* brow = xs + lr * 200u;
    float cthA, sthA, cthB, sthB;
    __sincosf(PI2 * (float)k2 * 0.01f, &sthA, &cthA);
    __sincosf(PI2 * (float)(k2 + 1) * 0.01f, &sthB, &cthB);
    float cA = 1.0f, sA = 0.0f, cB = 1.0f, sB = 0.0f;
    float reA = 0.f, imA = 0.f, reB = 0.f, imB = 0.f;
#pragma unroll 4
    for (int n2i = 0; n2i < 100; n2i += 2) {
      const float4 b0 = *(const float4*)(brow + 2 * n2i);
      reA += b0.x * cA + b0.y * sA;  imA += b0.y * cA - b0.x * sA;
      reB += b0.x * cB + b0.y * sB;  imB += b0.y * cB - b0.x * sB;
      float cA1 = cA * cthA - sA * sthA, sA1 = sA * cthA + cA * sthA;
      float cB1 = cB * cthB - sB * sthB, sB1 = sB * cthB + cB * sthB;
      reA += b0.z * cA1 + b0.w * sA1;  imA += b0.w * cA1 - b0.z * sA1;
      reB += b0.z * cB1 + b0.w * sB1;  imB += b0.w * cB1 - b0.z * sB1;
      cA = cA1 * cthA - sA1 * sthA; sA = sA1 * cthA + cA1 * sthA;
      cB = cB1 * cthB - sB1 * sthB; sB = sB1 * cthB + cB1 * sthB;
    }
    unsigned kA = gk1 + 100u * k2;
    unsigned kB = gk1 + 100u * (k2 + 1);
    if (kA <= 5000u) spec[sig * FS + kA] = make_float2(reA, imA);
    if (kB <= 5000u) spec[sig * FS + kB] = make_float2(reB, imB);
  }
}

// ---------------- mix: b-tile 2, 640 blocks, serial Fp loads ----------------
__global__ void k_mix(const float2* __restrict__ spec,
                      const float* __restrict__ tmask, const float* __restrict__ rmask,
                      const int* __restrict__ aidx, const int* __restrict__ rpos,
                      float2* __restrict__ G) {
  __shared__ float2 FaS[10][256];
  __shared__ float2 FcS[256];
  __shared__ float tmS[2][128];
  __shared__ int   aiS[2][128];
  __shared__ float rmS[2][8];
  __shared__ int   rpS[2][8][2];
  int tid = threadIdx.x;
  int k = blockIdx.x * 256 + tid;
  int kc = k > 5000 ? 5000 : k;
  int b0 = blockIdx.y * 2;
#pragma unroll
  for (int a = 0; a < 10; ++a) FaS[a][tid] = spec[(128 + a) * FS + kc];
  FcS[tid] = spec[138 * FS + kc];
  for (int i = tid; i < 2 * 128; i += 256) {
    int bb = i >> 7, ss = i & 127;
    tmS[bb][ss] = tmask[(b0 + bb) * 128 + ss];
    aiS[bb][ss] = aidx[(b0 + bb) * 128 + ss];
  }
  if (tid < 16) {
    int bb = tid >> 3, rr = tid & 7;
    rmS[bb][rr] = rmask[(b0 + bb) * 8 + rr];
    rpS[bb][rr][0] = rpos[((b0 + bb) * 8 + rr) * 2 + 0];
    rpS[bb][rr][1] = rpos[((b0 + bb) * 8 + rr) * 2 + 1];
  }
  __syncthreads();
  float fr[2] = {}, fi[2] = {};
#pragma unroll 8
  for (int s = 0; s < 128; ++s) {
    float2 fp = spec[s * FS + kc];
#pragma unroll
    for (int b = 0; b < 2; ++b) {
      int a = aiS[b][s];
      float tm = tmS[b][s];
      float2 fa = FaS[a][tid];
      float tr = fa.x * fp.x - fa.y * fp.y;
      float ti = fa.x * fp.y + fa.y * fp.x;
      fr[b] += tm * tr;
      fi[b] += tm * ti;
    }
  }
  float2 fc = FcS[tid];
#pragma unroll
  for (int r = 0; r < 8; ++r) {
#pragma unroll
    for (int b = 0; b < 2; ++b) {
      int p0 = rpS[b][r][0], p1 = rpS[b][r][1];
      float rm = rmS[b][r];
      float2 f0 = spec[p0 * FS + kc];
      float2 f1 = spec[p1 * FS + kc];
      float tr = f0.x * f1.x - f0.y * f1.y;
      float ti = f0.x * f1.y + f0.y * f1.x;
      float ur = tr * fc.x - ti * fc.y;
      float ui = tr * fc.y + ti * fc.x;
      fr[b] += rm * ur;
      fi[b] += rm * ui;
    }
  }
  if (k <= 5000) {
#pragma unroll
    for (int b = 0; b < 2; ++b) {
      float fib = (k == 0 || k == 5000) ? 0.0f : fi[b];  // exact Hermitian guard
      G[(size_t)(b0 + b) * 10000 + k] = make_float2(fr[b], fib);
      if (k >= 1 && k <= 4999)
        G[(size_t)(b0 + b) * 10000 + (10000 - k)] = make_float2(fr[b], -fib);
    }
  }
}

// ---------------- inverse stage 1 (Hermitian-halved, LDS-staged, twiddle recurrence) ----------------
__global__ void k_i1(const float2* __restrict__ G, float2* __restrict__ Bi) {
  __shared__ float gs[10400];   // 100 rows x 52 complex (104 floats/row)
  unsigned sig = blockIdx.x;
  const float* gp = (const float*)(G + sig * 10000u);
  for (int i = threadIdx.x; i < 2600; i += 256) {
    int row = i / 26, c4 = i % 26;
    *(float4*)(gs + row * 104 + c4 * 4) = *(const float4*)(gp + row * 200 + c4 * 4);
  }
  __syncthreads();
  unsigned tt = blockIdx.y * 256u + threadIdx.x;
  if (tt >= 1300u) return;
  unsigned m1 = (tt / 26u) * 2u, n2 = (tt % 26u) * 2u;
  float cthA, sthA, cthB, sthB;
  __sincosf(PI2 * (float)m1 * 0.01f, &sthA, &cthA);
  __sincosf(PI2 * (float)(m1 + 1) * 0.01f, &sthB, &cthB);
  float cA = 1.0f, sA = 0.0f, cB = 1.0f, sB = 0.0f;
  float reA[2] = {}, imA[2] = {};
  float reB[2] = {}, imB[2] = {};
#pragma unroll 4
  for (int n1 = 0; n1 < 100; ++n1) {
    const float4 gv = *(const float4*)(gs + n1 * 104 + n2 * 2);
    reA[0] += gv.x * cA - gv.y * sA;  imA[0] += gv.y * cA + gv.x * sA;
    reB[0] += gv.z * cA - gv.w * sA;  imB[0] += gv.w * cA + gv.z * sA;
    reA[1] += gv.x * cB - gv.y * sB;  imA[1] += gv.y * cB + gv.x * sB;
    reB[1] += gv.z * cB - gv.w * sB;  imB[1] += gv.w * cB + gv.z * sB;
    float cA1 = cA * cthA - sA * sthA, sA1 = sA * cthA + cA * sthA;
    float cB1 = cB * cthB - sB * sthB, sB1 = sB * cthB + cB * sthB;
    cA = cA1; sA = sA1; cB = cB1; sB = sB1;
  }
  float w0 = (n2 == 0 || n2 == 50) ? 0.5f : 1.0f;
  float w1 = (n2 == 50) ? 0.0f : 1.0f;
#pragma unroll
  for (int i = 0; i < 2; ++i) {
    float sw0, cw0, sw1, cw1;
    __sincosf(PI2 * (float)(n2 * (m1 + i)) * 1e-4f, &sw0, &cw0);
    __sincosf(PI2 * (float)((n2 + 1) * (m1 + i)) * 1e-4f, &sw1, &cw1);
    float4 outv;
    outv.x = (reA[i] * cw0 - imA[i] * sw0) * w0;
    outv.y = (imA[i] * cw0 + reA[i] * sw0) * w0;
    outv.z = (reB[i] * cw1 - imB[i] * sw1) * w1;
    outv.w = (imB[i] * cw1 + reB[i] * sw1) * w1;
    *(float4*)((float*)Bi + (sig * 5200u + (m1 + i) * 52u + n2) * 2) = outv;
  }
}

// ---------------- inverse stage 2 (Hermitian-halved, LDS-staged, twiddle recurrence) ----------------
__global__ void k_i2(const float2* __restrict__ Bi, float* __restrict__ mol) {
  __shared__ float bs[10400];   // 100 rows x 52 complex
  unsigned sig = blockIdx.x;
  const float* bp = (const float*)Bi + sig * 10400u;
  for (int i = threadIdx.x; i < 2600; i += 256)
    *(float4*)(bs + 4 * i) = *(const float4*)(bp + 4 * i);
  __syncthreads();
  unsigned tt = blockIdx.y * 256u + threadIdx.x;
  if (tt >= 2500u) return;
  unsigned m1 = (tt / 50u) * 2u;
  unsigned m2 = (tt % 50u) * 2u;
  const float* b0 = bs + m1 * 104u;
  const float* b1 = b0 + 104;
  float cthA, sthA, cthB, sthB;
  __sincosf(PI2 * (float)m2 * 0.01f, &sthA, &cthA);
  __sincosf(PI2 * (float)(m2 + 1) * 0.01f, &sthB, &cthB);
  float cA = 1.0f, sA = 0.0f, cB = 1.0f, sB = 0.0f;
  float re[2][2] = {};
#pragma unroll 4
  for (int jj = 0; jj < 26; ++jj) {
    int n2 = 2 * jj;
    const float4 v0 = *(const float4*)(b0 + 2 * n2);
    const float4 v1 = *(const float4*)(b1 + 2 * n2);
    re[0][0] += v0.x * cA - v0.y * sA;
    re[1][0] += v1.x * cA - v1.y * sA;
    re[0][1] += v0.x * cB - v0.y * sB;
    re[1][1] += v1.x * cB - v1.y * sB;
    float cA1 = cA * cthA - sA * sthA, sA1 = sA * cthA + cA * sthA;
    float cB1 = cB * cthB - sB * sthB, sB1 = sB * cthB + cB * sthB;
    re[0][0] += v0.z * cA1 - v0.w * sA1;
    re[1][0] += v1.z * cA1 - v1.w * sA1;
    re[0][1] += v0.z * cB1 - v0.w * sB1;
    re[1][1] += v1.z * cB1 - v1.w * sB1;
    cA = cA1 * cthA - sA1 * sthA; sA = sA1 * cthA + cA1 * sthA;
    cB = cB1 * cthB - sB1 * sthB; sB = sB1 * cthB + cB1 * sthB;
  }
#pragma unroll
  for (int i = 0; i < 2; ++i)
#pragma unroll
    for (int j = 0; j < 2; ++j)
      mol[sig * 10000u + (m1 + i) + 100u * (m2 + j)] = re[i][j] * 2e-4f;
}

// ---------------- projection: 250 chunks of 40 (round-13 proven) ----------------
__global__ __launch_bounds__(256) void k_proj(const float* __restrict__ mol,
                                              const float* __restrict__ W,
                                              float* __restrict__ part) {
  __shared__ float molS[40 * 64];
  int tid = threadIdx.x;
  int d0 = blockIdx.x * 40;
  for (int i = tid; i < 40 * 64; i += 256)
    molS[i] = mol[(size_t)(i & 63) * 10000 + d0 + (i >> 6)];
  __syncthreads();
  int p0 = (tid & 63) * 4;
  int bh = (tid >> 6) * 16;
  float acc[4][16] = {};
  const float* w0 = W + (size_t)(p0 + 0) * 10000 + d0;
  const float* w1 = W + (size_t)(p0 + 1) * 10000 + d0;
  const float* w2 = W + (size_t)(p0 + 2) * 10000 + d0;
  const float* w3 = W + (size_t)(p0 + 3) * 10000 + d0;
#pragma unroll 4
  for (int dl = 0; dl < 40; ++dl) {
    const float wv[4] = {w0[dl], w1[dl], w2[dl], w3[dl]};
    const float4* m4 = (const float4*)(molS + dl * 64 + bh);
#pragma unroll
    for (int q = 0; q < 4; ++q) {
      float4 mv = m4[q];
#pragma unroll
      for (int pp = 0; pp < 4; ++pp) {
        acc[pp][4 * q + 0] += wv[pp] * mv.x;
        acc[pp][4 * q + 1] += wv[pp] * mv.y;
        acc[pp][4 * q + 2] += wv[pp] * mv.z;
        acc[pp][4 * q + 3] += wv[pp] * mv.w;
      }
    }
  }
#pragma unroll
  for (int b = 0; b < 16; ++b) {
    float4 v = make_float4(acc[0][b], acc[1][b], acc[2][b], acc[3][b]);
    *(float4*)(part + (size_t)blockIdx.x * 16384 + (bh + b) * 256 + p0) = v;
  }
}

// ---------------- reduce partials + bias: grid (64 b, 4 p-quarters), 64-thread blocks ----------------
__global__ __launch_bounds__(64) void k_red(const float* __restrict__ part,
                                            const float* __restrict__ bias,
                                            float* __restrict__ out) {
  int tid = threadIdx.x;
  int b = blockIdx.x;
  int p = blockIdx.y * 64 + tid;
  float acc = bias[p];
#pragma unroll 8
  for (int ch = 0; ch < 250; ++ch)
    acc += part[(size_t)ch * 16384 + b * 256 + p];
  out[b * 256 + p] = acc;
}

extern "C" void kernel_launch(void* const* d_in, const int* in_sizes, int n_in,
                              void* d_out, int out_size, void* d_ws, size_t ws_size,
                              hipStream_t stream) {
  const float* atom  = (const float*)d_in[0];   // [10,10000]
  const float* pos   = (const float*)d_in[1];   // [128,10000]
  const float* clo   = (const float*)d_in[2];   // [10000]
  const float* W     = (const float*)d_in[3];   // [256,10000]
  const float* bias  = (const float*)d_in[4];   // [256]
  const float* tmask = (const float*)d_in[5];   // [64,128]
  const float* rmask = (const float*)d_in[6];   // [64,8]
  const int*   aidx  = (const int*)d_in[7];     // [64,128]
  const int*   rpos  = (const int*)d_in[8];     // [64,8,2]
  float* out = (float*)d_out;                   // [64,256]

  char* ws = (char*)d_ws;
  size_t off = 0;
  auto alloc = [&](size_t n) { off = (off + 255) & ~(size_t)255; size_t o = off; off += n; return o; };
  char* regA   = ws + alloc(16777216);          // Bi (2.66MB) / partials (16.4MB)
  float2* Bi   = (float2*)regA;                 // i1/i2 use Bi before proj writes part
  float*  part = (float*)regA;
  float2* spec = (float2*)(ws + alloc((size_t)NSIG * FS * 8));
  float2* G    = (float2*)(ws + alloc((size_t)64 * 10000 * 8));
  float*  mol  = (float*)(ws + alloc((size_t)64 * 10000 * 4));

  k_fwd<<<dim3(NSIG, 6), dim3(256), 0, stream>>>(atom, pos, clo, spec);
  k_mix<<<dim3(20, 32), dim3(256), 0, stream>>>(spec, tmask, rmask, aidx, rpos, G);
  k_i1<<<dim3(64, 6), dim3(256), 0, stream>>>(G, Bi);
  k_i2<<<dim3(64, 10), dim3(256), 0, stream>>>(Bi, mol);
  k_proj<<<dim3(250), dim3(256), 0, stream>>>(mol, W, part);
  k_red<<<dim3(64, 4), dim3(64), 0, stream>>>(part, bias, out);
}

// Round 19
// 190.132 us; speedup vs baseline: 1.0267x; 1.0014x over previous
//
#include <hip/hip_runtime.h>

#define PI2 6.28318530717958647692f

// D = 10000 = 100 x 100; F = 5001; signals: 128 pos + 10 atom + 1 closure = 139
#define NSIG 139
#define FS   5120      // spectrum row stride (float2)

// ---------------- fused forward (f1+f2), Hermitian-paired, LDS-resident ----------------
__global__ __launch_bounds__(256) void k_fwd(
                     const float* __restrict__ atom, const float* __restrict__ pos,
                     const float* __restrict__ clo, float2* __restrict__ spec) {
  __shared__ float xs[5000];    // phase1: 50 x-rows; phase3: B rows (stride 200 floats)
  unsigned sig = blockIdx.x, q = blockIdx.y;
  unsigned k1base = q * 10u;
  unsigned nk1 = (k1base + 10u <= 51u) ? 10u : (51u - k1base);   // q=5 -> 1 (k1=50)
  const float* xb = (sig < 128u) ? (pos + sig * 10000u)
                   : ((sig < 138u) ? (atom + (sig - 128u) * 10000u) : clo);
  int tid = threadIdx.x;
  unsigned ntile1 = nk1 * 25u;
  unsigned k1l = tid / 25u, n2 = (tid % 25u) * 4u;
  bool have = (unsigned)tid < ntile1;
  unsigned k1 = k1base + k1l;
  float cth, sth;
  __sincosf(PI2 * (float)k1 * 0.01f, &sth, &cth);
  float c = 1.0f, s = 0.0f;
  float ar[4] = {}, as[4] = {};

  for (int h = 0; h < 2; ++h) {
    for (int i = tid; i < 1250; i += 256)
      *(float4*)(xs + 4 * i) = *(const float4*)(xb + h * 5000 + 4 * i);
    __syncthreads();
    if (have) {
#pragma unroll 5
      for (int n1l = 0; n1l < 50; ++n1l) {
        const float4 xv = *(const float4*)(xs + n1l * 100 + n2);
        ar[0] += xv.x * c; as[0] += xv.x * s;
        ar[1] += xv.y * c; as[1] += xv.y * s;
        ar[2] += xv.z * c; as[2] += xv.z * s;
        ar[3] += xv.w * c; as[3] += xv.w * s;
        float cn = c * cth - s * sth;
        float sn = s * cth + c * sth;
        c = cn; s = sn;
      }
    }
    __syncthreads();
  }

  if (have) {
    unsigned rb = (100u - k1) % 100u;
    float resA[8], resB[8];
#pragma unroll
    for (int j = 0; j < 4; ++j) {
      float swA, cwA, swB, cwB;
      __sincosf(PI2 * (float)((n2 + j) * k1) * 1e-4f, &swA, &cwA);
      __sincosf(PI2 * (float)((n2 + j) * rb) * 1e-4f, &swB, &cwB);
      resA[2 * j + 0] = ar[j] * cwA - as[j] * swA;
      resA[2 * j + 1] = -(as[j] * cwA + ar[j] * swA);
      resB[2 * j + 0] = ar[j] * cwB + as[j] * swB;
      resB[2 * j + 1] = as[j] * cwB - ar[j] * swB;
    }
    float* pA = xs + k1l * 200u + n2 * 2u;
    float* pB = xs + (nk1 + k1l) * 200u + n2 * 2u;
    *(float4*)(pA + 0) = make_float4(resA[0], resA[1], resA[2], resA[3]);
    *(float4*)(pA + 4) = make_float4(resA[4], resA[5], resA[6], resA[7]);
    *(float4*)(pB + 0) = make_float4(resB[0], resB[1], resB[2], resB[3]);
    *(float4*)(pB + 4) = make_float4(resB[4], resB[5], resB[6], resB[7]);
  }
  __syncthreads();

  unsigned nrow = 2u * nk1;
  unsigned ntile3 = nrow * 26u;
  for (unsigned t = tid; t < ntile3; t += 256u) {
    unsigned lr = t / 26u, k2 = (t % 26u) * 2u;
    unsigned gk1 = (lr < nk1) ? (k1base + lr) : ((100u - (k1base + (lr - nk1))) % 100u);
    const float* brow = xs + lr * 200u;
    float cthA, sthA, cthB, sthB;
    __sincosf(PI2 * (float)k2 * 0.01f, &sthA, &cthA);
    __sincosf(PI2 * (float)(k2 + 1) * 0.01f, &sthB, &cthB);
    float cA = 1.0f, sA = 0.0f, cB = 1.0f, sB = 0.0f;
    float reA = 0.f, imA = 0.f, reB = 0.f, imB = 0.f;
#pragma unroll 4
    for (int n2i = 0; n2i < 100; n2i += 2) {
      const float4 b0 = *(const float4*)(brow + 2 * n2i);
      reA += b0.x * cA + b0.y * sA;  imA += b0.y * cA - b0.x * sA;
      reB += b0.x * cB + b0.y * sB;  imB += b0.y * cB - b0.x * sB;
      float cA1 = cA * cthA - sA * sthA, sA1 = sA * cthA + cA * sthA;
      float cB1 = cB * cthB - sB * sthB, sB1 = sB * cthB + cB * sthB;
      reA += b0.z * cA1 + b0.w * sA1;  imA += b0.w * cA1 - b0.z * sA1;
      reB += b0.z * cB1 + b0.w * sB1;  imB += b0.w * cB1 - b0.z * sB1;
      cA = cA1 * cthA - sA1 * sthA; sA = sA1 * cthA + cA1 * sthA;
      cB = cB1 * cthB - sB1 * sthB; sB = sB1 * cthB + cB1 * sthB;
    }
    unsigned kA = gk1 + 100u * k2;
    unsigned kB = gk1 + 100u * (k2 + 1);
    if (kA <= 5000u) spec[sig * FS + kA] = make_float2(reA, imA);
    if (kB <= 5000u) spec[sig * FS + kB] = make_float2(reB, imB);
  }
}

// ---------------- mix: b-tile 2, 640 blocks, serial Fp loads ----------------
__global__ void k_mix(const float2* __restrict__ spec,
                      const float* __restrict__ tmask, const float* __restrict__ rmask,
                      const int* __restrict__ aidx, const int* __restrict__ rpos,
                      float2* __restrict__ G) {
  __shared__ float2 FaS[10][256];
  __shared__ float2 FcS[256];
  __shared__ float tmS[2][128];
  __shared__ int   aiS[2][128];
  __shared__ float rmS[2][8];
  __shared__ int   rpS[2][8][2];
  int tid = threadIdx.x;
  int k = blockIdx.x * 256 + tid;
  int kc = k > 5000 ? 5000 : k;
  int b0 = blockIdx.y * 2;
#pragma unroll
  for (int a = 0; a < 10; ++a) FaS[a][tid] = spec[(128 + a) * FS + kc];
  FcS[tid] = spec[138 * FS + kc];
  for (int i = tid; i < 2 * 128; i += 256) {
    int bb = i >> 7, ss = i & 127;
    tmS[bb][ss] = tmask[(b0 + bb) * 128 + ss];
    aiS[bb][ss] = aidx[(b0 + bb) * 128 + ss];
  }
  if (tid < 16) {
    int bb = tid >> 3, rr = tid & 7;
    rmS[bb][rr] = rmask[(b0 + bb) * 8 + rr];
    rpS[bb][rr][0] = rpos[((b0 + bb) * 8 + rr) * 2 + 0];
    rpS[bb][rr][1] = rpos[((b0 + bb) * 8 + rr) * 2 + 1];
  }
  __syncthreads();
  float fr[2] = {}, fi[2] = {};
#pragma unroll 8
  for (int s = 0; s < 128; ++s) {
    float2 fp = spec[s * FS + kc];
#pragma unroll
    for (int b = 0; b < 2; ++b) {
      int a = aiS[b][s];
      float tm = tmS[b][s];
      float2 fa = FaS[a][tid];
      float tr = fa.x * fp.x - fa.y * fp.y;
      float ti = fa.x * fp.y + fa.y * fp.x;
      fr[b] += tm * tr;
      fi[b] += tm * ti;
    }
  }
  float2 fc = FcS[tid];
#pragma unroll
  for (int r = 0; r < 8; ++r) {
#pragma unroll
    for (int b = 0; b < 2; ++b) {
      int p0 = rpS[b][r][0], p1 = rpS[b][r][1];
      float rm = rmS[b][r];
      float2 f0 = spec[p0 * FS + kc];
      float2 f1 = spec[p1 * FS + kc];
      float tr = f0.x * f1.x - f0.y * f1.y;
      float ti = f0.x * f1.y + f0.y * f1.x;
      float ur = tr * fc.x - ti * fc.y;
      float ui = tr * fc.y + ti * fc.x;
      fr[b] += rm * ur;
      fi[b] += rm * ui;
    }
  }
  if (k <= 5000) {
#pragma unroll
    for (int b = 0; b < 2; ++b) {
      float fib = (k == 0 || k == 5000) ? 0.0f : fi[b];  // exact Hermitian guard
      G[(size_t)(b0 + b) * 10000 + k] = make_float2(fr[b], fib);
      if (k >= 1 && k <= 4999)
        G[(size_t)(b0 + b) * 10000 + (10000 - k)] = make_float2(fr[b], -fib);
    }
  }
}

// ---------------- inverse stage 1: tile 1 m1 x 2 n2, quarter-staged G (10.4 KB) ----------------
// Block (sig, y) with y in [0,11): t = y*256+tid in [0,2600). G staged in FOUR 25-row
// quarters; recurrence re-init at quarter h is exact: e^{i*pi*m1*h/2} by (m1*h) mod 4.
__global__ __launch_bounds__(256) void k_i1(const float2* __restrict__ G,
                                            float2* __restrict__ Bi) {
  __shared__ float gs[2600];    // 25 G-rows x 52 complex (104 floats/row)
  unsigned sig = blockIdx.x;
  const float* gp = (const float*)(G + sig * 10000u);
  int tid = threadIdx.x;
  unsigned t = blockIdx.y * 256u + tid;
  bool have = t < 2600u;
  unsigned m1 = t / 26u, n2 = (t % 26u) * 2u;
  float cth, sth;
  __sincosf(PI2 * (float)m1 * 0.01f, &sth, &cth);
  float reA = 0.f, imA = 0.f, reB = 0.f, imB = 0.f;

  for (int h = 0; h < 4; ++h) {
    if (h) __syncthreads();
    for (int i = tid; i < 650; i += 256) {
      int row = i / 26, c4 = i % 26;
      *(float4*)(gs + row * 104 + c4 * 4) =
          *(const float4*)(gp + (h * 25 + row) * 200 + c4 * 4);
    }
    __syncthreads();
    if (have) {
      // start phase e^{+i*pi*m1*h/2}: exact by (m1*h) mod 4
      unsigned ph = (m1 * (unsigned)h) & 3u;
      float c = (ph == 0u) ? 1.0f : (ph == 2u) ? -1.0f : 0.0f;
      float s = (ph == 1u) ? 1.0f : (ph == 3u) ? -1.0f : 0.0f;
#pragma unroll 5
      for (int n1l = 0; n1l < 25; ++n1l) {
        const float4 gv = *(const float4*)(gs + n1l * 104 + n2 * 2);
        reA += gv.x * c - gv.y * s;  imA += gv.y * c + gv.x * s;
        reB += gv.z * c - gv.w * s;  imB += gv.w * c + gv.z * s;
        float cn = c * cth - s * sth;
        float sn = s * cth + c * sth;
        c = cn; s = sn;
      }
    }
  }
  if (have) {
    float w0 = (n2 == 0u || n2 == 50u) ? 0.5f : 1.0f;
    float w1 = (n2 == 50u) ? 0.0f : 1.0f;   // col 51 unused
    float sw0, cw0, sw1, cw1;
    __sincosf(PI2 * (float)(n2 * m1) * 1e-4f, &sw0, &cw0);
    __sincosf(PI2 * (float)((n2 + 1u) * m1) * 1e-4f, &sw1, &cw1);
    float4 outv;
    outv.x = (reA * cw0 - imA * sw0) * w0;
    outv.y = (imA * cw0 + reA * sw0) * w0;
    outv.z = (reB * cw1 - imB * sw1) * w1;
    outv.w = (imB * cw1 + reB * sw1) * w1;
    *(float4*)((float*)Bi + (sig * 5200u + m1 * 52u + n2) * 2) = outv;
  }
}

// ---------------- inverse stage 2: quarter-staged Bi (10.4 KB), tile 1 m1 x 2 m2 ----------------
// Block (sig, q, z): m1 in [25q, 25q+25); 1250 tiles over 5 z-splits.
__global__ __launch_bounds__(256) void k_i2(const float2* __restrict__ Bi,
                                            float* __restrict__ mol) {
  __shared__ float bs[2600];    // 25 Bi-rows x 52 complex
  unsigned sig = blockIdx.x, q = blockIdx.y;
  int tid = threadIdx.x;
  const float* bp = (const float*)Bi + sig * 10400u + q * 2600u;   // contiguous quarter
  for (int i = tid; i < 650; i += 256)
    *(float4*)(bs + 4 * i) = *(const float4*)(bp + 4 * i);
  __syncthreads();
  unsigned t = blockIdx.z * 256u + tid;
  if (t >= 1250u) return;
  unsigned m1l = t / 50u;              // 0..24
  unsigned m2 = (t % 50u) * 2u;        // fastest
  const float* b0 = bs + m1l * 104u;
  float cthA, sthA, cthB, sthB;
  __sincosf(PI2 * (float)m2 * 0.01f, &sthA, &cthA);
  __sincosf(PI2 * (float)(m2 + 1u) * 0.01f, &sthB, &cthB);
  float cA = 1.0f, sA = 0.0f, cB = 1.0f, sB = 0.0f;
  float r0 = 0.f, r1 = 0.f;
#pragma unroll 4
  for (int jj = 0; jj < 26; ++jj) {
    int n2i = 2 * jj;
    const float4 v0 = *(const float4*)(b0 + 2 * n2i);
    r0 += v0.x * cA - v0.y * sA;
    r1 += v0.x * cB - v0.y * sB;
    float cA1 = cA * cthA - sA * sthA, sA1 = sA * cthA + cA * sthA;
    float cB1 = cB * cthB - sB * sthB, sB1 = sB * cthB + cB * sthB;
    r0 += v0.z * cA1 - v0.w * sA1;
    r1 += v0.z * cB1 - v0.w * sB1;
    cA = cA1 * cthA - sA1 * sthA; sA = sA1 * cthA + cA1 * sthA;
    cB = cB1 * cthB - sB1 * sthB; sB = sB1 * cthB + cB1 * sthB;
  }
  unsigned m1 = q * 25u + m1l;
  mol[sig * 10000u + m1 + 100u * m2] = r0 * 2e-4f;
  mol[sig * 10000u + m1 + 100u * (m2 + 1u)] = r1 * 2e-4f;
}

// ---------------- projection: 250 chunks of 40 (round-13 proven) ----------------
__global__ __launch_bounds__(256) void k_proj(const float* __restrict__ mol,
                                              const float* __restrict__ W,
                                              float* __restrict__ part) {
  __shared__ float molS[40 * 64];
  int tid = threadIdx.x;
  int d0 = blockIdx.x * 40;
  for (int i = tid; i < 40 * 64; i += 256)
    molS[i] = mol[(size_t)(i & 63) * 10000 + d0 + (i >> 6)];
  __syncthreads();
  int p0 = (tid & 63) * 4;
  int bh = (tid >> 6) * 16;
  float acc[4][16] = {};
  const float* w0 = W + (size_t)(p0 + 0) * 10000 + d0;
  const float* w1 = W + (size_t)(p0 + 1) * 10000 + d0;
  const float* w2 = W + (size_t)(p0 + 2) * 10000 + d0;
  const float* w3 = W + (size_t)(p0 + 3) * 10000 + d0;
#pragma unroll 4
  for (int dl = 0; dl < 40; ++dl) {
    const float wv[4] = {w0[dl], w1[dl], w2[dl], w3[dl]};
    const float4* m4 = (const float4*)(molS + dl * 64 + bh);
#pragma unroll
    for (int q = 0; q < 4; ++q) {
      float4 mv = m4[q];
#pragma unroll
      for (int pp = 0; pp < 4; ++pp) {
        acc[pp][4 * q + 0] += wv[pp] * mv.x;
        acc[pp][4 * q + 1] += wv[pp] * mv.y;
        acc[pp][4 * q + 2] += wv[pp] * mv.z;
        acc[pp][4 * q + 3] += wv[pp] * mv.w;
      }
    }
  }
#pragma unroll
  for (int b = 0; b < 16; ++b) {
    float4 v = make_float4(acc[0][b], acc[1][b], acc[2][b], acc[3][b]);
    *(float4*)(part + (size_t)blockIdx.x * 16384 + (bh + b) * 256 + p0) = v;
  }
}

// ---------------- reduce partials + bias: grid (64 b, 4 p-quarters), 64-thread blocks ----------------
__global__ __launch_bounds__(64) void k_red(const float* __restrict__ part,
                                            const float* __restrict__ bias,
                                            float* __restrict__ out) {
  int tid = threadIdx.x;
  int b = blockIdx.x;
  int p = blockIdx.y * 64 + tid;
  float acc = bias[p];
#pragma unroll 8
  for (int ch = 0; ch < 250; ++ch)
    acc += part[(size_t)ch * 16384 + b * 256 + p];
  out[b * 256 + p] = acc;
}

extern "C" void kernel_launch(void* const* d_in, const int* in_sizes, int n_in,
                              void* d_out, int out_size, void* d_ws, size_t ws_size,
                              hipStream_t stream) {
  const float* atom  = (const float*)d_in[0];   // [10,10000]
  const float* pos   = (const float*)d_in[1];   // [128,10000]
  const float* clo   = (const float*)d_in[2];   // [10000]
  const float* W     = (const float*)d_in[3];   // [256,10000]
  const float* bias  = (const float*)d_in[4];   // [256]
  const float* tmask = (const float*)d_in[5];   // [64,128]
  const float* rmask = (const float*)d_in[6];   // [64,8]
  const int*   aidx  = (const int*)d_in[7];     // [64,128]
  const int*   rpos  = (const int*)d_in[8];     // [64,8,2]
  float* out = (float*)d_out;                   // [64,256]

  char* ws = (char*)d_ws;
  size_t off = 0;
  auto alloc = [&](size_t n) { off = (off + 255) & ~(size_t)255; size_t o = off; off += n; return o; };
  char* regA   = ws + alloc(16777216);          // Bi (2.66MB) / partials (16.4MB)
  float2* Bi   = (float2*)regA;                 // i1/i2 use Bi before proj writes part
  float*  part = (float*)regA;
  float2* spec = (float2*)(ws + alloc((size_t)NSIG * FS * 8));
  float2* G    = (float2*)(ws + alloc((size_t)64 * 10000 * 8));
  float*  mol  = (float*)(ws + alloc((size_t)64 * 10000 * 4));

  k_fwd<<<dim3(NSIG, 6), dim3(256), 0, stream>>>(atom, pos, clo, spec);
  k_mix<<<dim3(20, 32), dim3(256), 0, stream>>>(spec, tmask, rmask, aidx, rpos, G);
  k_i1<<<dim3(64, 11), dim3(256), 0, stream>>>(G, Bi);
  k_i2<<<dim3(64, 4, 5), dim3(256), 0, stream>>>(Bi, mol);
  k_proj<<<dim3(250), dim3(256), 0, stream>>>(mol, W, part);
  k_red<<<dim3(64, 4), dim3(64), 0, stream>>>(part, bias, out);
}